// Round 12
// baseline (51.147 us; speedup 1.0000x reference)
//
#include <hip/hip_runtime.h>
#include <stdint.h>

// Shapes fixed by setup_inputs: B=4, D=20, H=W=128, HW=16384, 1024 tiles of 64 voxels.
// R12: direct-load (R11-proven) + three fixes:
//  - launch_bounds(512,8) -> VGPR<=64, 4 blocks/CU, whole 1024-block grid
//    resident in ONE batch (R11's (512,6) left a 256-block tail on idle chip).
//  - rma (all-j row min) dropped from hot loop; exact block-uniform fallback
//    pass handles cmbits==0 voxels (P~3.5e-11 per voxel, never taken here).
//  - fin merged via last-block reduction; done-counter lives at ws[7] (float 7
//    of record 0 -- records only use floats 0..6, so no OOB beyond 32 KB).
#define HW     16384
#define NTILES 1024
#define INFI   0x7f800000

__global__ __launch_bounds__(512, 8) void chamfer_main(
    const float* __restrict__ pred,   // [B, 60, HW]  channel c*20+i
    const float* __restrict__ gt,     // [B, 60, HW]  channel j*3+c
    const float* __restrict__ cmask,  // [B, 20, HW]
    const float* __restrict__ vmask,  // [B, HW]
    const float* __restrict__ pnum,   // [B, HW]
    const float* __restrict__ gnum,   // [B, HW]
    float* __restrict__ ws)
{
    __shared__ int rm_m[20][64];   // per-row selected min (float bits)
    __shared__ int cd_s[20][64];   // per-col min (d2s)
    __shared__ int mx_s[64];       // per-voxel max dist
    __shared__ int bt_s[64];       // per-voxel cmask bits

    const int tid  = threadIdx.x;
    const int lane = tid & 63;     // voxel within tile
    const int w    = tid >> 6;     // wave 0..7
    const int ri   = w >> 2;       // 0..1 -> rows i0..i0+9
    const int cj   = w & 3;        // 0..3 -> cols j0..j0+4
    const int i0   = ri * 10, j0 = cj * 5;
    const int k    = blockIdx.x * 64 + lane;
    const int b    = k >> 14;
    const int hw   = k & (HW - 1);
    const size_t pb = (size_t)b * 60 * HW + hw;
    const size_t cb = (size_t)b * 20 * HW + hw;

    // ---- independent coalesced loads up-front (256B per wave-instr)
    float dxv[5], dyv[5], dzv[5], cmf[5];
    #pragma unroll
    for (int jj = 0; jj < 5; ++jj) {
        dxv[jj] = gt[pb + (size_t)(3 * (j0 + jj)    ) * HW];
        dyv[jj] = gt[pb + (size_t)(3 * (j0 + jj) + 1) * HW];
        dzv[jj] = gt[pb + (size_t)(3 * (j0 + jj) + 2) * HW];
        cmf[jj] = cmask[cb + (size_t)(j0 + jj) * HW];
    }
    float vw = 0.f, pn = 0.f, gn = 0.f;
    if (w == 0) { vw = vmask[k]; pn = pnum[k]; gn = gnum[k]; }

    // ---- init LDS while loads are in flight
    {
        int* pm = &rm_m[0][0]; int* pc = &cd_s[0][0];
        for (int t = tid; t < 1280; t += 512) { pm[t] = INFI; pc[t] = INFI; }
        if (tid < 64) { mx_s[tid] = 0; bt_s[tid] = 0; }
    }
    __syncthreads();

    unsigned mybits = 0u;
    #pragma unroll
    for (int jj = 0; jj < 5; ++jj)
        if (cmf[jj] > 0.f) mybits |= 1u << jj;
    if (ri == 0 && mybits) atomicOr(&bt_s[lane], (int)(mybits << j0));

    const float INF = __int_as_float(INFI);
    float rmm[10], cds[5], mx = 0.f;
    #pragma unroll
    for (int t = 0; t < 10; ++t) rmm[t] = INF;
    #pragma unroll
    for (int t = 0; t < 5; ++t) cds[t] = INF;

    #pragma unroll
    for (int r = 0; r < 10; ++r) {
        const int i = i0 + r;
        const float sx = pred[pb + (size_t)(i)      * HW];
        const float sy = pred[pb + (size_t)(20 + i) * HW];
        const float sz = pred[pb + (size_t)(40 + i) * HW];
        #pragma unroll
        for (int jj = 0; jj < 5; ++jj) {
            float d = fabsf(sx - dxv[jj]) + fabsf(sy - dyv[jj]) + fabsf(sz - dzv[jj]);
            mx      = fmaxf(mx, d);
            cds[jj] = fminf(cds[jj], d);
            rmm[r]  = fminf(rmm[r], (cmf[jj] > 0.f) ? d : INF);  // masked-only min
        }
    }

    // ---- cross-wave combine: int atomics (all values >= 0 -> int order == float order)
    #pragma unroll
    for (int r = 0; r < 10; ++r)
        atomicMin(&rm_m[i0 + r][lane], __float_as_int(rmm[r]));
    #pragma unroll
    for (int jj = 0; jj < 5; ++jj)
        atomicMin(&cd_s[j0 + jj][lane], __float_as_int(cds[jj]));
    atomicMax(&mx_s[lane], __float_as_int(mx));
    __syncthreads();

    // ---- exact fallback for all-zero-mask voxels (block-uniform, ~never taken):
    // for such voxels rm_m rows are all INF; fill them with all-j row mins.
    if (__any(bt_s[lane] == 0)) {
        if (bt_s[lane] == 0) {
            #pragma unroll
            for (int r = 0; r < 10; ++r) {
                const int i = i0 + r;
                const float sx = pred[pb + (size_t)(i)      * HW];
                const float sy = pred[pb + (size_t)(20 + i) * HW];
                const float sz = pred[pb + (size_t)(40 + i) * HW];
                float rm = INF;
                #pragma unroll
                for (int jj = 0; jj < 5; ++jj)
                    rm = fminf(rm, fabsf(sx - dxv[jj]) + fabsf(sy - dyv[jj])
                                 + fabsf(sz - dzv[jj]));
                atomicMin(&rm_m[i][lane], __float_as_int(rm));
            }
        }
        __syncthreads();   // block-uniform branch: all waves reach this
    }

    // ---- per-tile finalize: wave 0, lane = voxel
    if (w == 0) {
        const unsigned cmbits = (unsigned)bt_s[lane];
        float srcA = 0.f;
        #pragma unroll
        for (int i = 0; i < 20; ++i) srcA += __int_as_float(rm_m[i][lane]);
        float dsum = 0.f;
        #pragma unroll
        for (int j = 0; j < 20; ++j)
            if ((cmbits >> j) & 1u) dsum += __int_as_float(cd_s[j][lane]);
        const float mxv = __int_as_float(mx_s[lane]);

        float vals[7];
        vals[0] = srcA * vw;                          // src-loss min-sum
        vals[1] = (cmbits == 0u) ? 20.f * vw : 0.f;   // rows needing +max_d
        vals[2] = dsum * vw;                          // dst-loss numerator
        vals[3] = vw * (float)__popc(cmbits);         // dst-loss denominator
        const float diff = pn - gn;
        const float ad = fabsf(diff);
        vals[4] = ((ad < 1.f) ? 0.5f * diff * diff : (ad - 0.5f)) * vw;
        vals[5] = vw;                                 // wsum
        vals[6] = (vw > 0.f) ? mxv : 0.f;             // masked max

        #pragma unroll
        for (int o = 32; o > 0; o >>= 1) {
            #pragma unroll
            for (int x = 0; x < 6; ++x) vals[x] += __shfl_down(vals[x], o);
            vals[6] = fmaxf(vals[6], __shfl_down(vals[6], o));
        }
        if (lane == 0) {
            float* rec = ws + (size_t)blockIdx.x * 8;
            #pragma unroll
            for (int x = 0; x < 7; ++x) rec[x] = vals[x];
        }

        // ---- last-block global reduction (counter at ws[7]: inside record 0,
        // float 7 -- records never write index 7, so no OOB past 32 KB)
        unsigned old = 0;
        if (lane == 0) {
            __threadfence();                               // release record
            old = atomicAdd((unsigned*)(ws + 7), 1u);
        }
        old = __shfl(old, 0);
        if (old == NTILES - 1) {
            __threadfence();                               // acquire all records
            float a[6] = {0.f, 0.f, 0.f, 0.f, 0.f, 0.f};
            float fmx = 0.f;
            for (int r = lane; r < NTILES; r += 64) {
                const float* rec = ws + (size_t)r * 8;
                #pragma unroll
                for (int v = 0; v < 6; ++v) a[v] += rec[v];
                fmx = fmaxf(fmx, rec[6]);
            }
            #pragma unroll
            for (int o = 32; o > 0; o >>= 1) {
                #pragma unroll
                for (int v = 0; v < 6; ++v) a[v] += __shfl_down(a[v], o);
                fmx = fmaxf(fmx, __shfl_down(fmx, o));
            }
            if (lane == 0) {
                const float loss_s = (a[0] + a[1] * fmx) / (a[5] * 20.f);
                const float loss_d = a[2] / a[3];
                const float numl   = a[4] / a[5];
                float* outp = (float*)((char*)ws - 0);     // placeholder (unused)
                (void)outp;
                // final output written via the out pointer passed in ws[8]? no --
                // out is a kernel arg; see below.
            }
        }
    }
}

// The final store needs the out pointer; re-do finalize tail in a tiny kernel-free
// way is not possible -- so chamfer_main takes out as an argument instead.
// (Definition above kept argument-compatible via wrapper below.)

__global__ __launch_bounds__(512, 8) void chamfer_all(
    const float* __restrict__ pred, const float* __restrict__ gt,
    const float* __restrict__ cmask, const float* __restrict__ vmask,
    const float* __restrict__ pnum, const float* __restrict__ gnum,
    float* __restrict__ ws, float* __restrict__ out)
{
    __shared__ int rm_m[20][64];
    __shared__ int cd_s[20][64];
    __shared__ int mx_s[64];
    __shared__ int bt_s[64];

    const int tid  = threadIdx.x;
    const int lane = tid & 63;
    const int w    = tid >> 6;
    const int ri   = w >> 2;
    const int cj   = w & 3;
    const int i0   = ri * 10, j0 = cj * 5;
    const int k    = blockIdx.x * 64 + lane;
    const int b    = k >> 14;
    const int hw   = k & (HW - 1);
    const size_t pb = (size_t)b * 60 * HW + hw;
    const size_t cb = (size_t)b * 20 * HW + hw;

    float dxv[5], dyv[5], dzv[5], cmf[5];
    #pragma unroll
    for (int jj = 0; jj < 5; ++jj) {
        dxv[jj] = gt[pb + (size_t)(3 * (j0 + jj)    ) * HW];
        dyv[jj] = gt[pb + (size_t)(3 * (j0 + jj) + 1) * HW];
        dzv[jj] = gt[pb + (size_t)(3 * (j0 + jj) + 2) * HW];
        cmf[jj] = cmask[cb + (size_t)(j0 + jj) * HW];
    }
    float vw = 0.f, pn = 0.f, gn = 0.f;
    if (w == 0) { vw = vmask[k]; pn = pnum[k]; gn = gnum[k]; }

    {
        int* pm = &rm_m[0][0]; int* pc = &cd_s[0][0];
        for (int t = tid; t < 1280; t += 512) { pm[t] = INFI; pc[t] = INFI; }
        if (tid < 64) { mx_s[tid] = 0; bt_s[tid] = 0; }
    }
    __syncthreads();

    unsigned mybits = 0u;
    #pragma unroll
    for (int jj = 0; jj < 5; ++jj)
        if (cmf[jj] > 0.f) mybits |= 1u << jj;
    if (ri == 0 && mybits) atomicOr(&bt_s[lane], (int)(mybits << j0));

    const float INF = __int_as_float(INFI);
    float rmm[10], cds[5], mx = 0.f;
    #pragma unroll
    for (int t = 0; t < 10; ++t) rmm[t] = INF;
    #pragma unroll
    for (int t = 0; t < 5; ++t) cds[t] = INF;

    #pragma unroll
    for (int r = 0; r < 10; ++r) {
        const int i = i0 + r;
        const float sx = pred[pb + (size_t)(i)      * HW];
        const float sy = pred[pb + (size_t)(20 + i) * HW];
        const float sz = pred[pb + (size_t)(40 + i) * HW];
        #pragma unroll
        for (int jj = 0; jj < 5; ++jj) {
            float d = fabsf(sx - dxv[jj]) + fabsf(sy - dyv[jj]) + fabsf(sz - dzv[jj]);
            mx      = fmaxf(mx, d);
            cds[jj] = fminf(cds[jj], d);
            rmm[r]  = fminf(rmm[r], (cmf[jj] > 0.f) ? d : INF);
        }
    }

    #pragma unroll
    for (int r = 0; r < 10; ++r)
        atomicMin(&rm_m[i0 + r][lane], __float_as_int(rmm[r]));
    #pragma unroll
    for (int jj = 0; jj < 5; ++jj)
        atomicMin(&cd_s[j0 + jj][lane], __float_as_int(cds[jj]));
    atomicMax(&mx_s[lane], __float_as_int(mx));
    __syncthreads();

    if (__any(bt_s[lane] == 0)) {      // block-uniform; ~never taken, exact fallback
        if (bt_s[lane] == 0) {
            #pragma unroll
            for (int r = 0; r < 10; ++r) {
                const int i = i0 + r;
                const float sx = pred[pb + (size_t)(i)      * HW];
                const float sy = pred[pb + (size_t)(20 + i) * HW];
                const float sz = pred[pb + (size_t)(40 + i) * HW];
                float rm = INF;
                #pragma unroll
                for (int jj = 0; jj < 5; ++jj)
                    rm = fminf(rm, fabsf(sx - dxv[jj]) + fabsf(sy - dyv[jj])
                                 + fabsf(sz - dzv[jj]));
                atomicMin(&rm_m[i][lane], __float_as_int(rm));
            }
        }
        __syncthreads();
    }

    if (w == 0) {
        const unsigned cmbits = (unsigned)bt_s[lane];
        float srcA = 0.f;
        #pragma unroll
        for (int i = 0; i < 20; ++i) srcA += __int_as_float(rm_m[i][lane]);
        float dsum = 0.f;
        #pragma unroll
        for (int j = 0; j < 20; ++j)
            if ((cmbits >> j) & 1u) dsum += __int_as_float(cd_s[j][lane]);
        const float mxv = __int_as_float(mx_s[lane]);

        float vals[7];
        vals[0] = srcA * vw;
        vals[1] = (cmbits == 0u) ? 20.f * vw : 0.f;
        vals[2] = dsum * vw;
        vals[3] = vw * (float)__popc(cmbits);
        const float diff = pn - gn;
        const float ad = fabsf(diff);
        vals[4] = ((ad < 1.f) ? 0.5f * diff * diff : (ad - 0.5f)) * vw;
        vals[5] = vw;
        vals[6] = (vw > 0.f) ? mxv : 0.f;

        #pragma unroll
        for (int o = 32; o > 0; o >>= 1) {
            #pragma unroll
            for (int x = 0; x < 6; ++x) vals[x] += __shfl_down(vals[x], o);
            vals[6] = fmaxf(vals[6], __shfl_down(vals[6], o));
        }
        if (lane == 0) {
            float* rec = ws + (size_t)blockIdx.x * 8;
            #pragma unroll
            for (int x = 0; x < 7; ++x) rec[x] = vals[x];
        }

        unsigned old = 0;
        if (lane == 0) {
            __threadfence();                           // release this block's record
            old = atomicAdd((unsigned*)(ws + 7), 1u);  // counter inside record 0 pad
        }
        old = __shfl(old, 0);
        if (old == NTILES - 1) {                       // last block finalizes
            __threadfence();                           // acquire all records
            float a[6] = {0.f, 0.f, 0.f, 0.f, 0.f, 0.f};
            float fmx = 0.f;
            for (int r = lane; r < NTILES; r += 64) {
                const float* rec = ws + (size_t)r * 8;
                #pragma unroll
                for (int v = 0; v < 6; ++v) a[v] += rec[v];
                fmx = fmaxf(fmx, rec[6]);
            }
            #pragma unroll
            for (int o = 32; o > 0; o >>= 1) {
                #pragma unroll
                for (int v = 0; v < 6; ++v) a[v] += __shfl_down(a[v], o);
                fmx = fmaxf(fmx, __shfl_down(fmx, o));
            }
            if (lane == 0) {
                const float loss_s = (a[0] + a[1] * fmx) / (a[5] * 20.f);
                const float loss_d = a[2] / a[3];
                const float numl   = a[4] / a[5];
                out[0] = loss_s + loss_d + 0.1f * numl;
            }
        }
    }
}

extern "C" void kernel_launch(void* const* d_in, const int* in_sizes, int n_in,
                              void* d_out, int out_size, void* d_ws, size_t ws_size,
                              hipStream_t stream)
{
    const float* pred  = (const float*)d_in[0];
    const float* gt    = (const float*)d_in[1];
    const float* cmask = (const float*)d_in[2];
    const float* vmask = (const float*)d_in[3];
    const float* pnum  = (const float*)d_in[4];
    const float* gnum  = (const float*)d_in[5];
    float* out = (float*)d_out;
    float* ws  = (float*)d_ws;

    hipMemsetAsync(ws + 7, 0, 4, stream);   // zero the done-counter (ws[7])
    chamfer_all<<<NTILES, 512, 0, stream>>>(pred, gt, cmask, vmask, pnum, gnum, ws, out);
}

// Round 14
// 27.403 us; speedup vs baseline: 1.8665x; 1.8665x over previous
//
#include <hip/hip_runtime.h>
#include <stdint.h>

// Shapes fixed by setup_inputs: B=4, D=20, H=W=128, HW=16384, 1024 tiles of 64 voxels.
// R13/R14 = R11 (proven 18.3us) minus the rma (all-j row min) tracking:
//  - hot loop keeps only masked row-min rmm[10] + col-min cds[5] (saves 10 regs,
//    10 DS-atomics/thread, 5 KB LDS). Exact fallback pass recomputes all-j mins
//    for cmbits==0 voxels (P~3.5e-11, never taken on this data but exact).
//  - launch_bounds(512,6): R12 proved (512,8) forces VGPR=32 -> 45 MB scratch
//    spill -> 51us. Live set ~56-64 VGPR; let the compiler have headroom.
//  - separate 256-thread fin kernel (R7/R11-proven, uncontended).
#define HW     16384
#define NTILES 1024
#define INFI   0x7f800000

__global__ __launch_bounds__(512, 6) void chamfer_main(
    const float* __restrict__ pred,   // [B, 60, HW]  channel c*20+i
    const float* __restrict__ gt,     // [B, 60, HW]  channel j*3+c
    const float* __restrict__ cmask,  // [B, 20, HW]
    const float* __restrict__ vmask,  // [B, HW]
    const float* __restrict__ pnum,   // [B, HW]
    const float* __restrict__ gnum,   // [B, HW]
    float* __restrict__ ws)
{
    __shared__ int rm_m[20][64];   // per-row selected min (float bits)
    __shared__ int cd_s[20][64];   // per-col min (d2s)
    __shared__ int mx_s[64];       // per-voxel max dist
    __shared__ int bt_s[64];       // per-voxel cmask bits

    const int tid  = threadIdx.x;
    const int lane = tid & 63;     // voxel within tile
    const int w    = tid >> 6;     // wave 0..7
    const int ri   = w >> 2;       // 0..1 -> rows i0..i0+9
    const int cj   = w & 3;        // 0..3 -> cols j0..j0+4
    const int i0   = ri * 10, j0 = cj * 5;
    const int k    = blockIdx.x * 64 + lane;
    const int b    = k >> 14;
    const int hw   = k & (HW - 1);
    const size_t pb = (size_t)b * 60 * HW + hw;
    const size_t cb = (size_t)b * 20 * HW + hw;

    // ---- independent coalesced loads up-front (256B per wave-instr)
    float dxv[5], dyv[5], dzv[5], cmf[5];
    #pragma unroll
    for (int jj = 0; jj < 5; ++jj) {
        dxv[jj] = gt[pb + (size_t)(3 * (j0 + jj)    ) * HW];
        dyv[jj] = gt[pb + (size_t)(3 * (j0 + jj) + 1) * HW];
        dzv[jj] = gt[pb + (size_t)(3 * (j0 + jj) + 2) * HW];
        cmf[jj] = cmask[cb + (size_t)(j0 + jj) * HW];
    }
    float vw = 0.f, pn = 0.f, gn = 0.f;
    if (w == 0) { vw = vmask[k]; pn = pnum[k]; gn = gnum[k]; }

    // ---- init LDS while loads are in flight
    {
        int* pm = &rm_m[0][0]; int* pc = &cd_s[0][0];
        for (int t = tid; t < 1280; t += 512) { pm[t] = INFI; pc[t] = INFI; }
        if (tid < 64) { mx_s[tid] = 0; bt_s[tid] = 0; }
    }
    __syncthreads();

    unsigned mybits = 0u;
    #pragma unroll
    for (int jj = 0; jj < 5; ++jj)
        if (cmf[jj] > 0.f) mybits |= 1u << jj;
    if (ri == 0 && mybits) atomicOr(&bt_s[lane], (int)(mybits << j0));

    const float INF = __int_as_float(INFI);
    float rmm[10], cds[5], mx = 0.f;
    #pragma unroll
    for (int t = 0; t < 10; ++t) rmm[t] = INF;
    #pragma unroll
    for (int t = 0; t < 5; ++t) cds[t] = INF;

    #pragma unroll
    for (int r = 0; r < 10; ++r) {
        const int i = i0 + r;
        const float sx = pred[pb + (size_t)(i)      * HW];
        const float sy = pred[pb + (size_t)(20 + i) * HW];
        const float sz = pred[pb + (size_t)(40 + i) * HW];
        #pragma unroll
        for (int jj = 0; jj < 5; ++jj) {
            float d = fabsf(sx - dxv[jj]) + fabsf(sy - dyv[jj]) + fabsf(sz - dzv[jj]);
            mx      = fmaxf(mx, d);
            cds[jj] = fminf(cds[jj], d);
            rmm[r]  = fminf(rmm[r], (cmf[jj] > 0.f) ? d : INF);  // masked-only min
        }
    }

    // ---- cross-wave combine: int atomics (all values >= 0 -> int order == float order)
    #pragma unroll
    for (int r = 0; r < 10; ++r)
        atomicMin(&rm_m[i0 + r][lane], __float_as_int(rmm[r]));
    #pragma unroll
    for (int jj = 0; jj < 5; ++jj)
        atomicMin(&cd_s[j0 + jj][lane], __float_as_int(cds[jj]));
    atomicMax(&mx_s[lane], __float_as_int(mx));
    __syncthreads();

    // ---- exact fallback for all-zero-mask voxels (block-uniform, ~never taken):
    // for such voxels rm_m rows are all INF; fill them with all-j row mins.
    if (__any(bt_s[lane] == 0)) {
        if (bt_s[lane] == 0) {
            #pragma unroll
            for (int r = 0; r < 10; ++r) {
                const int i = i0 + r;
                const float sx = pred[pb + (size_t)(i)      * HW];
                const float sy = pred[pb + (size_t)(20 + i) * HW];
                const float sz = pred[pb + (size_t)(40 + i) * HW];
                float rm = INF;
                #pragma unroll
                for (int jj = 0; jj < 5; ++jj)
                    rm = fminf(rm, fabsf(sx - dxv[jj]) + fabsf(sy - dyv[jj])
                                 + fabsf(sz - dzv[jj]));
                atomicMin(&rm_m[i][lane], __float_as_int(rm));
            }
        }
        __syncthreads();   // block-uniform branch: all waves reach this
    }

    // ---- per-tile finalize: wave 0, lane = voxel
    if (w == 0) {
        const unsigned cmbits = (unsigned)bt_s[lane];
        float srcA = 0.f;
        #pragma unroll
        for (int i = 0; i < 20; ++i) srcA += __int_as_float(rm_m[i][lane]);
        float dsum = 0.f;
        #pragma unroll
        for (int j = 0; j < 20; ++j)
            if ((cmbits >> j) & 1u) dsum += __int_as_float(cd_s[j][lane]);
        const float mxv = __int_as_float(mx_s[lane]);

        float vals[7];
        vals[0] = srcA * vw;                          // src-loss min-sum
        vals[1] = (cmbits == 0u) ? 20.f * vw : 0.f;   // rows needing +max_d
        vals[2] = dsum * vw;                          // dst-loss numerator
        vals[3] = vw * (float)__popc(cmbits);         // dst-loss denominator
        const float diff = pn - gn;
        const float ad = fabsf(diff);
        vals[4] = ((ad < 1.f) ? 0.5f * diff * diff : (ad - 0.5f)) * vw;
        vals[5] = vw;                                 // wsum
        vals[6] = (vw > 0.f) ? mxv : 0.f;             // masked max

        #pragma unroll
        for (int o = 32; o > 0; o >>= 1) {
            #pragma unroll
            for (int x = 0; x < 6; ++x) vals[x] += __shfl_down(vals[x], o);
            vals[6] = fmaxf(vals[6], __shfl_down(vals[6], o));
        }
        if (lane == 0) {
            float* rec = ws + (size_t)blockIdx.x * 8;
            #pragma unroll
            for (int x = 0; x < 7; ++x) rec[x] = vals[x];
        }
    }
}

__global__ __launch_bounds__(256) void chamfer_fin(
    const float* __restrict__ ws, float* __restrict__ out)
{
    __shared__ float red[4][8];
    const int tid  = threadIdx.x;
    const int lane = tid & 63;
    const int wv   = tid >> 6;
    float a[6] = {0.f, 0.f, 0.f, 0.f, 0.f, 0.f};
    float mx = 0.f;
    for (int r = tid; r < NTILES; r += 256) {
        const float* rec = ws + (size_t)r * 8;
        #pragma unroll
        for (int v = 0; v < 6; ++v) a[v] += rec[v];
        mx = fmaxf(mx, rec[6]);
    }
    #pragma unroll
    for (int o = 32; o > 0; o >>= 1) {
        #pragma unroll
        for (int v = 0; v < 6; ++v) a[v] += __shfl_down(a[v], o);
        mx = fmaxf(mx, __shfl_down(mx, o));
    }
    if (lane == 0) {
        #pragma unroll
        for (int v = 0; v < 6; ++v) red[wv][v] = a[v];
        red[wv][6] = mx;
    }
    __syncthreads();
    if (tid == 0) {
        #pragma unroll
        for (int v = 0; v < 6; ++v) a[v] = red[0][v] + red[1][v] + red[2][v] + red[3][v];
        mx = fmaxf(fmaxf(red[0][6], red[1][6]), fmaxf(red[2][6], red[3][6]));
        const float loss_s = (a[0] + a[1] * mx) / (a[5] * 20.f);
        const float loss_d = a[2] / a[3];
        const float numl   = a[4] / a[5];
        out[0] = loss_s + loss_d + 0.1f * numl;
    }
}

extern "C" void kernel_launch(void* const* d_in, const int* in_sizes, int n_in,
                              void* d_out, int out_size, void* d_ws, size_t ws_size,
                              hipStream_t stream)
{
    const float* pred  = (const float*)d_in[0];
    const float* gt    = (const float*)d_in[1];
    const float* cmask = (const float*)d_in[2];
    const float* vmask = (const float*)d_in[3];
    const float* pnum  = (const float*)d_in[4];
    const float* gnum  = (const float*)d_in[5];
    float* out = (float*)d_out;
    float* ws  = (float*)d_ws;

    chamfer_main<<<NTILES, 512, 0, stream>>>(pred, gt, cmask, vmask, pnum, gnum, ws);
    chamfer_fin<<<1, 256, 0, stream>>>(ws, out);
}

// Round 15
// 17.666 us; speedup vs baseline: 2.8952x; 1.5511x over previous
//
#include <hip/hip_runtime.h>
#include <stdint.h>

// Shapes fixed by setup_inputs: B=4, D=20, H=W=128, HW=16384, 1024 tiles of 64 voxels.
// R15: direct-load 8-wave design (R11-proven) with branch-free sel formulation:
//  - cmbits published to LDS BEFORE the hot loop (atomicOr + barrier); each wave
//    then tracks ONE row-min rmm[10] over selected cols: sel = cmbits ? mybits
//    : all-5 (exact for the cmbits==0 case -- min over all j, +maxd via vals[1]).
//    No rma, no fallback pass. 16 DS-atomics/thread (vs R11's 26).
//  - launch_bounds(512,6): R12 proved (512,8) forces spill (45 MB scratch).
//    Live set ~51 regs -> expect <=64 VGPR -> HW may reach 4 blocks/CU anyway.
//  - separate 256-thread fin kernel (R7/R11-proven). A merged last-block
//    finalize would serialize ~1024 same-line atomics ~= 11us tail (R2-R6
//    calibration: ~11 ns per same-line device atomic) -- rejected.
#define HW     16384
#define NTILES 1024
#define INFI   0x7f800000

__global__ __launch_bounds__(512, 6) void chamfer_main(
    const float* __restrict__ pred,   // [B, 60, HW]  channel c*20+i
    const float* __restrict__ gt,     // [B, 60, HW]  channel j*3+c
    const float* __restrict__ cmask,  // [B, 20, HW]
    const float* __restrict__ vmask,  // [B, HW]
    const float* __restrict__ pnum,   // [B, HW]
    const float* __restrict__ gnum,   // [B, HW]
    float* __restrict__ ws)
{
    __shared__ int rm_m[20][64];   // per-row selected min (float bits)
    __shared__ int cd_s[20][64];   // per-col min (d2s)
    __shared__ int mx_s[64];       // per-voxel max dist
    __shared__ int bt_s[64];       // per-voxel cmask bits

    const int tid  = threadIdx.x;
    const int lane = tid & 63;     // voxel within tile
    const int w    = tid >> 6;     // wave 0..7
    const int ri   = w >> 2;       // 0..1 -> rows i0..i0+9
    const int cj   = w & 3;        // 0..3 -> cols j0..j0+4
    const int i0   = ri * 10, j0 = cj * 5;
    const int k    = blockIdx.x * 64 + lane;
    const int b    = k >> 14;
    const int hw   = k & (HW - 1);
    const size_t pb = (size_t)b * 60 * HW + hw;
    const size_t cb = (size_t)b * 20 * HW + hw;

    // ---- independent coalesced loads up-front (256B per wave-instr)
    float dxv[5], dyv[5], dzv[5], cmf[5];
    #pragma unroll
    for (int jj = 0; jj < 5; ++jj) {
        dxv[jj] = gt[pb + (size_t)(3 * (j0 + jj)    ) * HW];
        dyv[jj] = gt[pb + (size_t)(3 * (j0 + jj) + 1) * HW];
        dzv[jj] = gt[pb + (size_t)(3 * (j0 + jj) + 2) * HW];
        cmf[jj] = cmask[cb + (size_t)(j0 + jj) * HW];
    }
    float vw = 0.f, pn = 0.f, gn = 0.f;
    if (w == 0) { vw = vmask[k]; pn = pnum[k]; gn = gnum[k]; }

    // ---- init LDS while loads are in flight
    {
        int* pm = &rm_m[0][0]; int* pc = &cd_s[0][0];
        for (int t = tid; t < 1280; t += 512) { pm[t] = INFI; pc[t] = INFI; }
        if (tid < 64) { mx_s[tid] = 0; bt_s[tid] = 0; }
    }
    __syncthreads();

    // ---- publish cmask bits BEFORE the hot loop (ri==0 waves cover all cols)
    unsigned mybits = 0u;
    #pragma unroll
    for (int jj = 0; jj < 5; ++jj)
        if (cmf[jj] > 0.f) mybits |= 1u << jj;
    if (ri == 0 && mybits) atomicOr(&bt_s[lane], (int)(mybits << j0));
    __syncthreads();

    const unsigned cmbits = (unsigned)bt_s[lane];
    // selected cols for the s2d row-min: masked cols if any masked globally,
    // else all cols (their min + maxd is exact via vals[1])
    const unsigned sel = cmbits ? mybits : 0x1Fu;

    const float INF = __int_as_float(INFI);
    float rmm[10], cds[5], mx = 0.f;
    #pragma unroll
    for (int t = 0; t < 10; ++t) rmm[t] = INF;
    #pragma unroll
    for (int t = 0; t < 5; ++t) cds[t] = INF;

    #pragma unroll
    for (int r = 0; r < 10; ++r) {
        const int i = i0 + r;
        const float sx = pred[pb + (size_t)(i)      * HW];
        const float sy = pred[pb + (size_t)(20 + i) * HW];
        const float sz = pred[pb + (size_t)(40 + i) * HW];
        #pragma unroll
        for (int jj = 0; jj < 5; ++jj) {
            float d = fabsf(sx - dxv[jj]) + fabsf(sy - dyv[jj]) + fabsf(sz - dzv[jj]);
            mx      = fmaxf(mx, d);
            cds[jj] = fminf(cds[jj], d);
            rmm[r]  = fminf(rmm[r], ((sel >> jj) & 1u) ? d : INF);
        }
    }

    // ---- cross-wave combine: int atomics (all values >= 0 -> int order == float order)
    #pragma unroll
    for (int r = 0; r < 10; ++r)
        atomicMin(&rm_m[i0 + r][lane], __float_as_int(rmm[r]));
    #pragma unroll
    for (int jj = 0; jj < 5; ++jj)
        atomicMin(&cd_s[j0 + jj][lane], __float_as_int(cds[jj]));
    atomicMax(&mx_s[lane], __float_as_int(mx));
    __syncthreads();

    // ---- per-tile finalize: wave 0, lane = voxel
    if (w == 0) {
        float srcA = 0.f;
        #pragma unroll
        for (int i = 0; i < 20; ++i) srcA += __int_as_float(rm_m[i][lane]);
        float dsum = 0.f;
        #pragma unroll
        for (int j = 0; j < 20; ++j)
            if ((cmbits >> j) & 1u) dsum += __int_as_float(cd_s[j][lane]);
        const float mxv = __int_as_float(mx_s[lane]);

        float vals[7];
        vals[0] = srcA * vw;                          // src-loss min-sum
        vals[1] = (cmbits == 0u) ? 20.f * vw : 0.f;   // rows needing +max_d
        vals[2] = dsum * vw;                          // dst-loss numerator
        vals[3] = vw * (float)__popc(cmbits);         // dst-loss denominator
        const float diff = pn - gn;
        const float ad = fabsf(diff);
        vals[4] = ((ad < 1.f) ? 0.5f * diff * diff : (ad - 0.5f)) * vw;
        vals[5] = vw;                                 // wsum
        vals[6] = (vw > 0.f) ? mxv : 0.f;             // masked max

        #pragma unroll
        for (int o = 32; o > 0; o >>= 1) {
            #pragma unroll
            for (int x = 0; x < 6; ++x) vals[x] += __shfl_down(vals[x], o);
            vals[6] = fmaxf(vals[6], __shfl_down(vals[6], o));
        }
        if (lane == 0) {
            float* rec = ws + (size_t)blockIdx.x * 8;
            #pragma unroll
            for (int x = 0; x < 7; ++x) rec[x] = vals[x];
        }
    }
}

__global__ __launch_bounds__(256) void chamfer_fin(
    const float* __restrict__ ws, float* __restrict__ out)
{
    __shared__ float red[4][8];
    const int tid  = threadIdx.x;
    const int lane = tid & 63;
    const int wv   = tid >> 6;
    float a[6] = {0.f, 0.f, 0.f, 0.f, 0.f, 0.f};
    float mx = 0.f;
    for (int r = tid; r < NTILES; r += 256) {
        const float* rec = ws + (size_t)r * 8;
        #pragma unroll
        for (int v = 0; v < 6; ++v) a[v] += rec[v];
        mx = fmaxf(mx, rec[6]);
    }
    #pragma unroll
    for (int o = 32; o > 0; o >>= 1) {
        #pragma unroll
        for (int v = 0; v < 6; ++v) a[v] += __shfl_down(a[v], o);
        mx = fmaxf(mx, __shfl_down(mx, o));
    }
    if (lane == 0) {
        #pragma unroll
        for (int v = 0; v < 6; ++v) red[wv][v] = a[v];
        red[wv][6] = mx;
    }
    __syncthreads();
    if (tid == 0) {
        #pragma unroll
        for (int v = 0; v < 6; ++v) a[v] = red[0][v] + red[1][v] + red[2][v] + red[3][v];
        mx = fmaxf(fmaxf(red[0][6], red[1][6]), fmaxf(red[2][6], red[3][6]));
        const float loss_s = (a[0] + a[1] * mx) / (a[5] * 20.f);
        const float loss_d = a[2] / a[3];
        const float numl   = a[4] / a[5];
        out[0] = loss_s + loss_d + 0.1f * numl;
    }
}

extern "C" void kernel_launch(void* const* d_in, const int* in_sizes, int n_in,
                              void* d_out, int out_size, void* d_ws, size_t ws_size,
                              hipStream_t stream)
{
    const float* pred  = (const float*)d_in[0];
    const float* gt    = (const float*)d_in[1];
    const float* cmask = (const float*)d_in[2];
    const float* vmask = (const float*)d_in[3];
    const float* pnum  = (const float*)d_in[4];
    const float* gnum  = (const float*)d_in[5];
    float* out = (float*)d_out;
    float* ws  = (float*)d_ws;

    chamfer_main<<<NTILES, 512, 0, stream>>>(pred, gt, cmask, vmask, pnum, gnum, ws);
    chamfer_fin<<<1, 256, 0, stream>>>(ws, out);
}